// Round 4
// baseline (748.155 us; speedup 1.0000x reference)
//
#include <hip/hip_runtime.h>

#define NN 500000      // nodes
#define NE 500000      // edges
#define EPB 128        // edges per block in gemm_scatter

typedef _Float16 half8 __attribute__((ext_vector_type(8)));
typedef float floatx4 __attribute__((ext_vector_type(4)));

// All scratch lives in module-static device memory: no d_ws dependence
// (previous rounds' container crashes are suspected ws_size overruns),
// no hipMemsetAsync during graph capture. Every array below is fully
// rewritten on every call before any read of it.
__device__ __align__(16) ushort g_wt[128 * 128];   // pre-swizzled W^T (f16 bits)
__device__ float    g_ssrc[NN];
__device__ float    g_sdst[NN];
__device__ float    g_alpha[NE];
__device__ unsigned g_maxenc;
__device__ float    g_denom;

// ---------------------------------------------------------------------------
// zero d_out (atomic accumulator) — 16,000,000 float4 = 62500 blocks x 256
// ---------------------------------------------------------------------------
__global__ __launch_bounds__(256) void k_zero(float4* __restrict__ p) {
  p[(size_t)blockIdx.x * 256 + threadIdx.x] = make_float4(0.f, 0.f, 0.f, 0.f);
}

// ---------------------------------------------------------------------------
// W (128x128 f32, W[k][j]) -> g_wt as W^T in f16, pre-swizzled:
// wt[j*128 + (k ^ ((j&7)<<3))] = (f16) W[k][j]
// so a linear copy into LDS yields the swizzled layout directly.
// Also zero-inits the softmax scalars (stream order guarantees visibility).
// ---------------------------------------------------------------------------
__global__ __launch_bounds__(256) void k_prep_w(const float* __restrict__ w) {
  int idx = blockIdx.x * 256 + threadIdx.x;   // 16384 total
  if (idx == 0) { g_maxenc = 0u; g_denom = 0.f; }
  int k = idx >> 7, j = idx & 127;
  union { _Float16 h; ushort u; } cv;
  cv.h = (_Float16)w[k * 128 + j];
  g_wt[j * 128 + (k ^ ((j & 7) << 3))] = cv.u;
}

// ---------------------------------------------------------------------------
// Fused GEMM + scatter: for a tile of 128 edges, gather x[col[e]] rows into
// LDS (f32->f16), MFMA against W^T, atomicAdd the 128x128 result into
// out[row[e]][:].  out must be pre-zeroed.
// ---------------------------------------------------------------------------
__global__ __launch_bounds__(256) void k_gemm_scatter(
    const float* __restrict__ x, const int* __restrict__ ei,
    float* __restrict__ out) {
  __shared__ __align__(16) ushort Ah[EPB * 128];   // swizzled A tile (f16 bits)
  __shared__ __align__(16) ushort Wh[128 * 128];   // swizzled W^T (f16 bits)
  __shared__ int rowids[EPB];
  __shared__ int colids[EPB];

  const int tid = threadIdx.x;
  const int base = blockIdx.x * EPB;

  // edge ids for this tile
  if (tid < EPB) {
    int e = base + tid;
    int re = -1, ce = 0;
    if (e < NE) { re = ei[e]; ce = ei[NE + e]; }
    rowids[tid] = re;
    colids[tid] = ce;
  }
  // copy pre-swizzled W^T f16 (32KB) linearly into LDS
  {
    const uint4* w4 = (const uint4*)g_wt;
    uint4* wl4 = (uint4*)Wh;
#pragma unroll
    for (int i = 0; i < 8; ++i) wl4[tid + 256 * i] = w4[tid + 256 * i];
  }
  __syncthreads();   // colids ready

  // stage A: gather x rows, convert to f16, swizzled store
  {
    const float4* x4 = (const float4*)x;
#pragma unroll
    for (int it = 0; it < (EPB * 32) / 256; ++it) {
      int i = tid + it * 256;
      int e = i >> 5, seg = i & 31;
      int cn = colids[e];
      float4 v = x4[cn * 32 + seg];
      union { _Float16 h[4]; uint2 u; } p;
      p.h[0] = (_Float16)v.x; p.h[1] = (_Float16)v.y;
      p.h[2] = (_Float16)v.z; p.h[3] = (_Float16)v.w;
      int hidx = (seg * 4) ^ ((e & 7) << 3);
      *(uint2*)&Ah[e * 128 + hidx] = p.u;
    }
  }
  __syncthreads();

  // compute: wave w handles 32 edges x 128 cols
  const int wid = tid >> 6;
  const int lane = tid & 63;
  const int l15 = lane & 15;
  const int lg = lane >> 4;          // k-group 0..3
  const int ebase = wid * 32;

  floatx4 acc[2][8] = {};
#pragma unroll
  for (int kk = 0; kk < 4; ++kk) {
    const int k0 = kk * 32 + lg * 8;
    half8 a[2], b[8];
#pragma unroll
    for (int m = 0; m < 2; ++m) {
      int e = ebase + m * 16 + l15;
      a[m] = *(const half8*)&Ah[e * 128 + (k0 ^ ((e & 7) << 3))];
    }
#pragma unroll
    for (int n = 0; n < 8; ++n) {
      int j = n * 16 + l15;
      b[n] = *(const half8*)&Wh[j * 128 + (k0 ^ ((j & 7) << 3))];
    }
#pragma unroll
    for (int n = 0; n < 8; ++n)
#pragma unroll
      for (int m = 0; m < 2; ++m)
        acc[m][n] = __builtin_amdgcn_mfma_f32_16x16x32_f16(a[m], b[n], acc[m][n], 0, 0, 0);
  }

  // epilogue: atomicAdd into out[row[e]][:]
#pragma unroll
  for (int m = 0; m < 2; ++m) {
#pragma unroll
    for (int r = 0; r < 4; ++r) {
      int el = ebase + m * 16 + lg * 4 + r;
      int rn = rowids[el];
      if (rn >= 0) {
        float* orow = out + (size_t)rn * 128;
#pragma unroll
        for (int n = 0; n < 8; ++n)
          unsafeAtomicAdd(&orow[n * 16 + l15], acc[m][n][r]);
      }
    }
  }
}

// ---------------------------------------------------------------------------
// Per-node: v = relu(accum + bias); s_src = v . a_src ; s_dst = v . a_dst
// (does NOT write back relu'd rows; k_scale recomputes them)
// 8 rows per block, 32 lanes per row.
// ---------------------------------------------------------------------------
__global__ __launch_bounds__(256) void k_rowdots(
    const float* __restrict__ out, const float* __restrict__ att,
    const float* __restrict__ bias) {
  int tid = threadIdx.x;
  int lane32 = tid & 31;
  int row = blockIdx.x * 8 + (tid >> 5);
  const float4* o4 = (const float4*)out;
  const float4* b4 = (const float4*)bias;
  const float4* as4 = (const float4*)att;
  const float4* ad4 = (const float4*)(att + 128);
  float4 v = o4[(size_t)row * 32 + lane32];
  float4 bb = b4[lane32];
  v.x = fmaxf(v.x + bb.x, 0.f); v.y = fmaxf(v.y + bb.y, 0.f);
  v.z = fmaxf(v.z + bb.z, 0.f); v.w = fmaxf(v.w + bb.w, 0.f);
  float4 as = as4[lane32], ad = ad4[lane32];
  float ps = v.x * as.x + v.y * as.y + v.z * as.z + v.w * as.w;
  float pd = v.x * ad.x + v.y * ad.y + v.z * ad.z + v.w * ad.w;
#pragma unroll
  for (int off = 16; off; off >>= 1) {
    ps += __shfl_xor(ps, off);
    pd += __shfl_xor(pd, off);
  }
  if (lane32 == 0) { g_ssrc[row] = ps; g_sdst[row] = pd; }
}

// ---------------------------------------------------------------------------
// alpha[e] = leaky_relu(s_src[row]+s_dst[col]); global max via encoded atomicMax
// ---------------------------------------------------------------------------
__device__ __forceinline__ unsigned enc_f32(float x) {
  unsigned u = __float_as_uint(x);
  return (u & 0x80000000u) ? ~u : (u | 0x80000000u);
}

__global__ __launch_bounds__(256) void k_alpha_max(const int* __restrict__ ei) {
  int e = blockIdx.x * 256 + threadIdx.x;
  float a = -3.4e38f;
  if (e < NE) {
    int r = ei[e], c = ei[NE + e];
    float v = g_ssrc[r] + g_sdst[c];
    a = v > 0.f ? v : 0.2f * v;
    g_alpha[e] = a;
  }
#pragma unroll
  for (int off = 32; off; off >>= 1) a = fmaxf(a, __shfl_xor(a, off));
  __shared__ float wm[4];
  if ((threadIdx.x & 63) == 0) wm[threadIdx.x >> 6] = a;
  __syncthreads();
  if (threadIdx.x == 0) {
    float m = fmaxf(fmaxf(wm[0], wm[1]), fmaxf(wm[2], wm[3]));
    atomicMax(&g_maxenc, enc_f32(m));
  }
}

// ---------------------------------------------------------------------------
// alpha[e] = exp(alpha[e]-max); global sum via atomicAdd
// ---------------------------------------------------------------------------
__global__ __launch_bounds__(256) void k_exp_sum() {
  unsigned encv = g_maxenc;
  unsigned u = (encv & 0x80000000u) ? (encv & 0x7fffffffu) : ~encv;
  float mx = __uint_as_float(u);
  int e = blockIdx.x * 256 + threadIdx.x;
  float v = 0.f;
  if (e < NE) {
    v = expf(g_alpha[e] - mx);
    g_alpha[e] = v;
  }
#pragma unroll
  for (int off = 32; off; off >>= 1) v += __shfl_xor(v, off);
  __shared__ float wsum[4];
  if ((threadIdx.x & 63) == 0) wsum[threadIdx.x >> 6] = v;
  __syncthreads();
  if (threadIdx.x == 0) atomicAdd(&g_denom, wsum[0] + wsum[1] + wsum[2] + wsum[3]);
}

// ---------------------------------------------------------------------------
// d_out[i][f] = relu(accum[i][f]+bias[f]) * alpha[i]/denom   (in-place)
// ---------------------------------------------------------------------------
__global__ __launch_bounds__(256) void k_scale(
    float* __restrict__ out, const float* __restrict__ bias) {
  int idx = blockIdx.x * 256 + threadIdx.x;   // over 16,000,000 float4
  int row = idx >> 5;
  float sc = g_alpha[row] / g_denom;
  float4* o4 = (float4*)out;
  const float4* b4 = (const float4*)bias;
  float4 bb = b4[idx & 31];
  float4 v = o4[idx];
  v.x = fmaxf(v.x + bb.x, 0.f) * sc;
  v.y = fmaxf(v.y + bb.y, 0.f) * sc;
  v.z = fmaxf(v.z + bb.z, 0.f) * sc;
  v.w = fmaxf(v.w + bb.w, 0.f) * sc;
  o4[idx] = v;
}

extern "C" void kernel_launch(void* const* d_in, const int* in_sizes, int n_in,
                              void* d_out, int out_size, void* d_ws, size_t ws_size,
                              hipStream_t stream) {
  const float* x    = (const float*)d_in[0];
  const int*   ei   = (const int*)d_in[1];
  const float* w    = (const float*)d_in[2];
  const float* att  = (const float*)d_in[3];
  const float* bias = (const float*)d_in[4];
  float* out = (float*)d_out;
  (void)d_ws; (void)ws_size; (void)in_sizes; (void)n_in; (void)out_size;

  k_zero<<<62500, 256, 0, stream>>>((float4*)out);           // accumulator zero
  k_prep_w<<<64, 256, 0, stream>>>(w);                       // + maxenc/denom init
  k_gemm_scatter<<<(NE + EPB - 1) / EPB, 256, 0, stream>>>(x, ei, out);
  k_rowdots<<<NN / 8, 256, 0, stream>>>(out, att, bias);
  k_alpha_max<<<(NE + 255) / 256, 256, 0, stream>>>(ei);
  k_exp_sum<<<(NE + 255) / 256, 256, 0, stream>>>();
  k_scale<<<NN * 32 / 256, 256, 0, stream>>>(out, bias);
}